// Round 6
// baseline (174.309 us; speedup 1.0000x reference)
//
#include <hip/hip_runtime.h>

// qkv: (4, 8192, 3, 16, 64) f32 ; out: (4, 8192, 16, 64) f32
constexpr int   Bn    = 4;
constexpr int   Nn    = 8192;
constexpr int   Hn    = 16;
constexpr int   Dn    = 64;
constexpr int   ROW   = 3 * Hn * Dn;                   // 3072 floats = 12 KB
constexpr long long QKV_B = (long long)Nn * ROW;       // 25165824
constexpr int   OUT_N = Hn * Dn;                       // 1024
constexpr long long OUT_B = (long long)Nn * OUT_N;     // 8388608
constexpr long long OUT_TOT = (long long)Bn * OUT_B;   // 33554432

using v4f = __attribute__((ext_vector_type(4))) float;
using v4u = __attribute__((ext_vector_type(4))) unsigned int;

// x + dpp_move(x): fuses to a single v_add_f32_dpp (no LDS pipe).
template<int CTRL>
__device__ __forceinline__ float dpp_add(float x) {
  int mv = __builtin_amdgcn_update_dpp(0, __float_as_int(x), CTRL, 0xF, 0xF, true);
  return x + __int_as_float(mv);
}
// Sum across a 16-lane DPP row: quad_perm xor1 (0xB1), xor2 (0x4E), row_ror:4, row_ror:8.
__device__ __forceinline__ float row16_sum(float x) {
  x = dpp_add<0xB1>(x);
  x = dpp_add<0x4E>(x);
  x = dpp_add<0x124>(x);
  x = dpp_add<0x128>(x);
  return x;
}

__device__ __forceinline__ unsigned short f2bf_rne(float x) {
  unsigned u = __float_as_uint(x);
  u += 0x7FFFu + ((u >> 16) & 1u);
  return (unsigned short)(u >> 16);
}

struct Frag {
  float q[4][4], k[4][4], v[4][4];
};

__device__ __forceinline__ void load_frag(Frag& f, const float* __restrict__ qb,
                                          int j) {
#pragma unroll
  for (int m = 0; m < 4; ++m) {
    const float* rp = qb + (size_t)(m * 2048 + j) * ROW;
    float4 t;
    t = *(const float4*)(rp);
    f.q[m][0] = t.x; f.q[m][1] = t.y; f.q[m][2] = t.z; f.q[m][3] = t.w;
    t = *(const float4*)(rp + 1024);
    f.k[m][0] = t.x; f.k[m][1] = t.y; f.k[m][2] = t.z; f.k[m][3] = t.w;
    t = *(const float4*)(rp + 2048);
    f.v[m][0] = t.x; f.v[m][1] = t.y; f.v[m][2] = t.z; f.v[m][3] = t.w;
  }
}

template<bool USE_BF16>
__device__ __forceinline__ void compute_frag(const Frag& f, int j, size_t obase,
                                             float* __restrict__ out,
                                             unsigned short* __restrict__ ws16,
                                             float* cs) {
  // 4x4 scores: per-lane d-quad partial, DPP 16-lane reduce.
  float S[4][4];
#pragma unroll
  for (int m = 0; m < 4; ++m)
#pragma unroll
    for (int m2 = 0; m2 < 4; ++m2) {
      float s = f.q[m][0] * f.k[m2][0] + f.q[m][1] * f.k[m2][1] +
                f.q[m][2] * f.k[m2][2] + f.q[m][3] * f.k[m2][3];
      S[m][m2] = row16_sum(s) * 0.125f;   // 1/sqrt(64)
    }

  float acc[4][4];

  // branch 1 (r=1): softmax over 4 keys, every position.
#pragma unroll
  for (int m = 0; m < 4; ++m) {
    float mx = fmaxf(fmaxf(S[m][0], S[m][1]), fmaxf(S[m][2], S[m][3]));
    float e0 = __expf(S[m][0] - mx);
    float e1 = __expf(S[m][1] - mx);
    float e2 = __expf(S[m][2] - mx);
    float e3 = __expf(S[m][3] - mx);
    float inv = 1.0f / (e0 + e1 + e2 + e3);
    e0 *= inv; e1 *= inv; e2 *= inv; e3 *= inv;
#pragma unroll
    for (int c = 0; c < 4; ++c)
      acc[m][c] = e0 * f.v[0][c] + e1 * f.v[1][c] +
                  e2 * f.v[2][c] + e3 * f.v[3][c];
  }

  // branch 2 (r=2): iff j even (block-uniform: j parity == it parity).
  if ((j & 1) == 0) {
#pragma unroll
    for (int m = 0; m < 4; ++m) {
      const int a  = m & 1;
      const int b2 = a + 2;
      float sa = S[m][a], sb = S[m][b2];
      float mx = fmaxf(sa, sb);
      float ea = __expf(sa - mx);
      float eb = __expf(sb - mx);
      float inv = 1.0f / (ea + eb);
      ea *= inv; eb *= inv;
#pragma unroll
      for (int c = 0; c < 4; ++c)
        acc[m][c] += ea * f.v[a][c] + eb * f.v[b2][c];
    }
  }

  // branch 3 (r=4): iff j % 4 == 0 (block-uniform).
  if ((j & 3) == 0) {
#pragma unroll
    for (int m = 0; m < 4; ++m)
#pragma unroll
      for (int c = 0; c < 4; ++c)
        acc[m][c] += f.v[m][c];
  }

  // store unnormalized (cacheable — re-read by scale pass); colsum partials.
#pragma unroll
  for (int m = 0; m < 4; ++m) {
    const size_t oi = obase + (size_t)(m * 2048 + j) * OUT_N;
    if (USE_BF16) {
      ushort4 st;
      st.x = f2bf_rne(acc[m][0]); st.y = f2bf_rne(acc[m][1]);
      st.z = f2bf_rne(acc[m][2]); st.w = f2bf_rne(acc[m][3]);
      *(ushort4*)(ws16 + oi) = st;
    } else {
      *(float4*)(out + oi) =
          make_float4(acc[m][0], acc[m][1], acc[m][2], acc[m][3]);
    }
    cs[0] += acc[m][0]; cs[1] += acc[m][1];
    cs[2] += acc[m][2]; cs[3] += acc[m][3];
  }
}

// Kernel 1: block = (b, chunk of 4 CONSECUTIVE j), all 16 heads; NO LDS;
// 2-deep software pipeline. Consecutive j => each m-stream is 48 KB fully
// contiguous (4x12 KB rows) and out/ws16 writes are 8 KB-contiguous runs.
template<bool USE_BF16>
__global__ __launch_bounds__(256) void dil_main(const float* __restrict__ qkv,
                                                float* __restrict__ out,
                                                unsigned short* __restrict__ ws16,
                                                double* __restrict__ colsum,
                                                int repMask) {
  const int tid  = threadIdx.x;
  const int h    = tid >> 4;
  const int t16  = tid & 15;
  const int bid  = blockIdx.x;     // 0..2047
  const int b    = bid >> 9;
  const int j0   = (bid & 511) * 4;   // first of 4 consecutive j

  const float* qb = qkv + (size_t)b * QKV_B + tid * 4;
  const size_t obase = (size_t)b * OUT_B + tid * 4;

  float cs[4] = {0.f, 0.f, 0.f, 0.f};

  Frag A, B;
  load_frag(A, qb, j0);                    // it 0
  load_frag(B, qb, j0 + 1);                // it 1 (in flight during compute 0)
  compute_frag<USE_BF16>(A, j0, obase, out, ws16, cs);
  load_frag(A, qb, j0 + 2);                // it 2
  compute_frag<USE_BF16>(B, j0 + 1, obase, out, ws16, cs);
  load_frag(B, qb, j0 + 3);                // it 3
  compute_frag<USE_BF16>(A, j0 + 2, obase, out, ws16, cs);
  compute_frag<USE_BF16>(B, j0 + 3, obase, out, ws16, cs);

  double* cp = colsum + (size_t)(bid & repMask) * 4096 +
               ((size_t)b * 16 + h) * 64 + t16 * 4;
  atomicAdd(cp + 0, (double)cs[0]);
  atomicAdd(cp + 1, (double)cs[1]);
  atomicAdd(cp + 2, (double)cs[2]);
  atomicAdd(cp + 3, (double)cs[3]);
}

// Kernel 2: reduce replicas + reciprocal table (4096 entries)
__global__ __launch_bounds__(256) void dil_recip(const double* __restrict__ colsum,
                                                 float* __restrict__ recip, int rep) {
  const int i = blockIdx.x * 256 + threadIdx.x;
  if (i < Bn * Hn * Dn) {
    double s = 0.0;
    for (int r = 0; r < rep; ++r) s += colsum[(size_t)r * 4096 + i];
    recip[i] = (float)(1.0 / s);
  }
}

// Kernel 3a: bf16 staging -> normalized f32 out. Thread handles 8 elems.
// nt-load the staging (never re-read), nt-store the output (never read) —
// preserves L3 capacity for qkv across replays.
__global__ __launch_bounds__(256) void dil_scale_bf16(const unsigned short* __restrict__ ws16,
                                                      float* __restrict__ out,
                                                      const float* __restrict__ recip) {
  const long long u = (long long)blockIdx.x * 256 + threadIdx.x;
  const long long e = u * 8;
  const int b  = (int)(e >> 23);
  const int h  = (int)((e >> 6) & 15);
  const int q8 = (int)((e >> 3) & 7);    // which d-octet

  const float4 r0 = ((const float4*)recip)[((b * 16 + h) << 4) + q8 * 2];
  const float4 r1 = ((const float4*)recip)[((b * 16 + h) << 4) + q8 * 2 + 1];

  const v4u raw = __builtin_nontemporal_load((const v4u*)(ws16 + e));
  v4f o0, o1;
  o0[0] = __uint_as_float((raw[0] & 0xFFFFu) << 16) * r0.x;
  o0[1] = __uint_as_float((raw[0] & 0xFFFF0000u))   * r0.y;
  o0[2] = __uint_as_float((raw[1] & 0xFFFFu) << 16) * r0.z;
  o0[3] = __uint_as_float((raw[1] & 0xFFFF0000u))   * r0.w;
  o1[0] = __uint_as_float((raw[2] & 0xFFFFu) << 16) * r1.x;
  o1[1] = __uint_as_float((raw[2] & 0xFFFF0000u))   * r1.y;
  o1[2] = __uint_as_float((raw[3] & 0xFFFFu) << 16) * r1.z;
  o1[3] = __uint_as_float((raw[3] & 0xFFFF0000u))   * r1.w;
  __builtin_nontemporal_store(o0, (v4f*)(out + e));
  __builtin_nontemporal_store(o1, (v4f*)(out + e + 4));
}

// Kernel 3b (fallback): in-place f32 scale
__global__ __launch_bounds__(256) void dil_scale_f32(float* __restrict__ out,
                                                     const float* __restrict__ recip) {
  const long long f = (long long)blockIdx.x * 256 + threadIdx.x;  // float4 index
  const int d4 = (int)(f & 15);
  const int h  = (int)((f >> 4) & 15);
  const int b  = (int)(f >> 21);
  const float4 r = ((const float4*)recip)[(b * 16 + h) * 16 + d4];
  float4 o = ((const float4*)out)[f];
  o.x *= r.x; o.y *= r.y; o.z *= r.z; o.w *= r.w;
  ((float4*)out)[f] = o;
}

extern "C" void kernel_launch(void* const* d_in, const int* in_sizes, int n_in,
                              void* d_out, int out_size, void* d_ws, size_t ws_size,
                              hipStream_t stream) {
  const float* qkv = (const float*)d_in[0];
  float* out = (float*)d_out;

  const size_t bf16_bytes = (size_t)OUT_TOT * 2;   // 67108864
  int rep = 32;
  bool use_bf16 = true;
  while (rep > 1 && bf16_bytes + (size_t)rep * 4096 * sizeof(double) +
                        4096 * sizeof(float) > ws_size)
    rep >>= 1;
  if (bf16_bytes + (size_t)rep * 4096 * sizeof(double) + 4096 * sizeof(float) >
      ws_size) {
    use_bf16 = false;
    rep = 32;
    while (rep > 1 && (size_t)rep * 4096 * sizeof(double) +
                          4096 * sizeof(float) > ws_size)
      rep >>= 1;
  }

  unsigned short* ws16 = (unsigned short*)d_ws;
  char* tail = (char*)d_ws + (use_bf16 ? bf16_bytes : 0);
  double* colsum = (double*)tail;
  float*  recip  = (float*)(tail + (size_t)rep * 4096 * sizeof(double));

  hipMemsetAsync(colsum, 0, (size_t)rep * 4096 * sizeof(double), stream);

  if (use_bf16)
    dil_main<true><<<2048, 256, 0, stream>>>(qkv, out, ws16, colsum, rep - 1);
  else
    dil_main<false><<<2048, 256, 0, stream>>>(qkv, out, ws16, colsum, rep - 1);

  dil_recip<<<16, 256, 0, stream>>>(colsum, recip, rep);

  if (use_bf16) {
    const long long nu = OUT_TOT / 8;              // 4194304 threads
    dil_scale_bf16<<<(int)(nu / 256), 256, 0, stream>>>(ws16, out, recip);
  } else {
    const long long nf4 = OUT_TOT / 4;
    dil_scale_f32<<<(int)(nf4 / 256), 256, 0, stream>>>(out, recip);
  }
}

// Round 7
// 155.787 us; speedup vs baseline: 1.1189x; 1.1189x over previous
//
#include <hip/hip_runtime.h>

// qkv: (4, 8192, 3, 16, 64) f32 ; out: (4, 8192, 16, 64) f32
constexpr int   Bn    = 4;
constexpr int   Nn    = 8192;
constexpr int   Hn    = 16;
constexpr int   Dn    = 64;
constexpr int   ROW   = 3 * Hn * Dn;                   // 3072 floats = 12 KB
constexpr long long QKV_B = (long long)Nn * ROW;       // 25165824
constexpr int   OUT_N = Hn * Dn;                       // 1024
constexpr long long OUT_B = (long long)Nn * OUT_N;     // 8388608
constexpr long long OUT_TOT = (long long)Bn * OUT_B;   // 33554432
constexpr int   NBLK  = 2048;                          // dil_main grid
constexpr int   BLKS_PER_B = 512;

using v4f = __attribute__((ext_vector_type(4))) float;
using v4u = __attribute__((ext_vector_type(4))) unsigned int;

// x + dpp_move(x): fuses to a single v_add_f32_dpp (no LDS pipe).
template<int CTRL>
__device__ __forceinline__ float dpp_add(float x) {
  int mv = __builtin_amdgcn_update_dpp(0, __float_as_int(x), CTRL, 0xF, 0xF, true);
  return x + __int_as_float(mv);
}
// Sum across a 16-lane DPP row: quad_perm xor1 (0xB1), xor2 (0x4E), row_ror:4, row_ror:8.
__device__ __forceinline__ float row16_sum(float x) {
  x = dpp_add<0xB1>(x);
  x = dpp_add<0x4E>(x);
  x = dpp_add<0x124>(x);
  x = dpp_add<0x128>(x);
  return x;
}

__device__ __forceinline__ unsigned short f2bf_rne(float x) {
  unsigned u = __float_as_uint(x);
  u += 0x7FFFu + ((u >> 16) & 1u);
  return (unsigned short)(u >> 16);
}

struct Frag {
  float q[4][4], k[4][4], v[4][4];
};

__device__ __forceinline__ void load_frag(Frag& f, const float* __restrict__ qb,
                                          int j) {
#pragma unroll
  for (int m = 0; m < 4; ++m) {
    const float* rp = qb + (size_t)(m * 2048 + j) * ROW;
    float4 t;
    t = *(const float4*)(rp);
    f.q[m][0] = t.x; f.q[m][1] = t.y; f.q[m][2] = t.z; f.q[m][3] = t.w;
    t = *(const float4*)(rp + 1024);
    f.k[m][0] = t.x; f.k[m][1] = t.y; f.k[m][2] = t.z; f.k[m][3] = t.w;
    t = *(const float4*)(rp + 2048);
    f.v[m][0] = t.x; f.v[m][1] = t.y; f.v[m][2] = t.z; f.v[m][3] = t.w;
  }
}

template<bool USE_BF16>
__device__ __forceinline__ void compute_frag(const Frag& f, int j, size_t obase,
                                             float* __restrict__ out,
                                             unsigned short* __restrict__ ws16,
                                             float* cs) {
  // 4x4 scores: per-lane d-quad partial, DPP 16-lane reduce.
  float S[4][4];
#pragma unroll
  for (int m = 0; m < 4; ++m)
#pragma unroll
    for (int m2 = 0; m2 < 4; ++m2) {
      float s = f.q[m][0] * f.k[m2][0] + f.q[m][1] * f.k[m2][1] +
                f.q[m][2] * f.k[m2][2] + f.q[m][3] * f.k[m2][3];
      S[m][m2] = row16_sum(s) * 0.125f;   // 1/sqrt(64)
    }

  float acc[4][4];

  // branch 1 (r=1): softmax over 4 keys, every position.
#pragma unroll
  for (int m = 0; m < 4; ++m) {
    float mx = fmaxf(fmaxf(S[m][0], S[m][1]), fmaxf(S[m][2], S[m][3]));
    float e0 = __expf(S[m][0] - mx);
    float e1 = __expf(S[m][1] - mx);
    float e2 = __expf(S[m][2] - mx);
    float e3 = __expf(S[m][3] - mx);
    float inv = 1.0f / (e0 + e1 + e2 + e3);
    e0 *= inv; e1 *= inv; e2 *= inv; e3 *= inv;
#pragma unroll
    for (int c = 0; c < 4; ++c)
      acc[m][c] = e0 * f.v[0][c] + e1 * f.v[1][c] +
                  e2 * f.v[2][c] + e3 * f.v[3][c];
  }

  // branch 2 (r=2): iff j even (block-uniform).
  if ((j & 1) == 0) {
#pragma unroll
    for (int m = 0; m < 4; ++m) {
      const int a  = m & 1;
      const int b2 = a + 2;
      float sa = S[m][a], sb = S[m][b2];
      float mx = fmaxf(sa, sb);
      float ea = __expf(sa - mx);
      float eb = __expf(sb - mx);
      float inv = 1.0f / (ea + eb);
      ea *= inv; eb *= inv;
#pragma unroll
      for (int c = 0; c < 4; ++c)
        acc[m][c] += ea * f.v[a][c] + eb * f.v[b2][c];
    }
  }

  // branch 3 (r=4): iff j % 4 == 0 (block-uniform).
  if ((j & 3) == 0) {
#pragma unroll
    for (int m = 0; m < 4; ++m)
#pragma unroll
      for (int c = 0; c < 4; ++c)
        acc[m][c] += f.v[m][c];
  }

  // store unnormalized; accumulate colsum partials in registers.
#pragma unroll
  for (int m = 0; m < 4; ++m) {
    const size_t oi = obase + (size_t)(m * 2048 + j) * OUT_N;
    if (USE_BF16) {
      ushort4 st;
      st.x = f2bf_rne(acc[m][0]); st.y = f2bf_rne(acc[m][1]);
      st.z = f2bf_rne(acc[m][2]); st.w = f2bf_rne(acc[m][3]);
      *(ushort4*)(ws16 + oi) = st;
    } else {
      *(float4*)(out + oi) =
          make_float4(acc[m][0], acc[m][1], acc[m][2], acc[m][3]);
    }
    cs[0] += acc[m][0]; cs[1] += acc[m][1];
    cs[2] += acc[m][2]; cs[3] += acc[m][3];
  }
}

// Kernel 1: block = (b, chunk of 4 consecutive j), all 16 heads; NO LDS;
// 2-deep software pipeline; NO ATOMICS — per-block colsum partials are
// written non-atomically as one contiguous 4 KB float4 store.
template<bool USE_BF16>
__global__ __launch_bounds__(256) void dil_main(const float* __restrict__ qkv,
                                                float* __restrict__ out,
                                                unsigned short* __restrict__ ws16,
                                                float* __restrict__ partial) {
  const int tid  = threadIdx.x;
  const int bid  = blockIdx.x;        // 0..2047
  const int b    = bid >> 9;
  const int j0   = (bid & 511) * 4;   // first of 4 consecutive j

  const float* qb = qkv + (size_t)b * QKV_B + tid * 4;
  const size_t obase = (size_t)b * OUT_B + tid * 4;

  float cs[4] = {0.f, 0.f, 0.f, 0.f};

  Frag A, B;
  load_frag(A, qb, j0);                    // it 0
  load_frag(B, qb, j0 + 1);                // it 1 (in flight during compute 0)
  compute_frag<USE_BF16>(A, j0, obase, out, ws16, cs);
  load_frag(A, qb, j0 + 2);                // it 2
  compute_frag<USE_BF16>(B, j0 + 1, obase, out, ws16, cs);
  load_frag(B, qb, j0 + 3);                // it 3
  compute_frag<USE_BF16>(A, j0 + 2, obase, out, ws16, cs);
  compute_frag<USE_BF16>(B, j0 + 3, obase, out, ws16, cs);

  // partial[bid][tid*4 .. tid*4+3]  — block writes 4 KB contiguous.
  *(float4*)(partial + (size_t)bid * 1024 + tid * 4) =
      make_float4(cs[0], cs[1], cs[2], cs[3]);
}

// Kernel 2: deterministic f64 tree-sum of the 512 per-block partials for
// each of the 4096 (b,h,d) columns, then reciprocal.
__global__ __launch_bounds__(256) void dil_recip(const float* __restrict__ partial,
                                                 float* __restrict__ recip) {
  const int i = blockIdx.x * 256 + threadIdx.x;   // 0..4095
  const int b = i >> 10;
  const int w = i & 1023;
  const float* p = partial + (size_t)b * BLKS_PER_B * 1024 + w;
  double s = 0.0;
  for (int r = 0; r < BLKS_PER_B; ++r)
    s += (double)p[(size_t)r * 1024];
  recip[i] = (float)(1.0 / s);
}

// Kernel 3a: bf16 staging -> normalized f32 out. Thread handles 8 elems.
__global__ __launch_bounds__(256) void dil_scale_bf16(const unsigned short* __restrict__ ws16,
                                                      float* __restrict__ out,
                                                      const float* __restrict__ recip) {
  const long long u = (long long)blockIdx.x * 256 + threadIdx.x;
  const long long e = u * 8;
  const int b  = (int)(e >> 23);
  const int h  = (int)((e >> 6) & 15);
  const int q8 = (int)((e >> 3) & 7);    // which d-octet

  const float4 r0 = ((const float4*)recip)[((b * 16 + h) << 4) + q8 * 2];
  const float4 r1 = ((const float4*)recip)[((b * 16 + h) << 4) + q8 * 2 + 1];

  const v4u raw = __builtin_nontemporal_load((const v4u*)(ws16 + e));
  v4f o0, o1;
  o0[0] = __uint_as_float((raw[0] & 0xFFFFu) << 16) * r0.x;
  o0[1] = __uint_as_float((raw[0] & 0xFFFF0000u))   * r0.y;
  o0[2] = __uint_as_float((raw[1] & 0xFFFFu) << 16) * r0.z;
  o0[3] = __uint_as_float((raw[1] & 0xFFFF0000u))   * r0.w;
  o1[0] = __uint_as_float((raw[2] & 0xFFFFu) << 16) * r1.x;
  o1[1] = __uint_as_float((raw[2] & 0xFFFF0000u))   * r1.y;
  o1[2] = __uint_as_float((raw[3] & 0xFFFFu) << 16) * r1.z;
  o1[3] = __uint_as_float((raw[3] & 0xFFFF0000u))   * r1.w;
  __builtin_nontemporal_store(o0, (v4f*)(out + e));
  __builtin_nontemporal_store(o1, (v4f*)(out + e + 4));
}

// Kernel 3b (fallback): in-place f32 scale
__global__ __launch_bounds__(256) void dil_scale_f32(float* __restrict__ out,
                                                     const float* __restrict__ recip) {
  const long long f = (long long)blockIdx.x * 256 + threadIdx.x;  // float4 index
  const int d4 = (int)(f & 15);
  const int h  = (int)((f >> 4) & 15);
  const int b  = (int)(f >> 21);
  const float4 r = ((const float4*)recip)[(b * 16 + h) * 16 + d4];
  float4 o = ((const float4*)out)[f];
  o.x *= r.x; o.y *= r.y; o.z *= r.z; o.w *= r.w;
  ((float4*)out)[f] = o;
}

extern "C" void kernel_launch(void* const* d_in, const int* in_sizes, int n_in,
                              void* d_out, int out_size, void* d_ws, size_t ws_size,
                              hipStream_t stream) {
  const float* qkv = (const float*)d_in[0];
  float* out = (float*)d_out;

  const size_t bf16_bytes    = (size_t)OUT_TOT * 2;            // 67108864
  const size_t partial_bytes = (size_t)NBLK * 1024 * 4;        // 8388608
  const size_t recip_bytes   = 4096 * sizeof(float);

  bool use_bf16 = (bf16_bytes + partial_bytes + recip_bytes) <= ws_size;

  unsigned short* ws16 = (unsigned short*)d_ws;
  char* tail = (char*)d_ws + (use_bf16 ? bf16_bytes : 0);
  float* partial = (float*)tail;
  float* recip   = (float*)(tail + partial_bytes);

  if (use_bf16)
    dil_main<true><<<NBLK, 256, 0, stream>>>(qkv, out, ws16, partial);
  else
    dil_main<false><<<NBLK, 256, 0, stream>>>(qkv, out, ws16, partial);

  dil_recip<<<16, 256, 0, stream>>>(partial, recip);

  if (use_bf16) {
    const long long nu = OUT_TOT / 8;              // 4194304 threads
    dil_scale_bf16<<<(int)(nu / 256), 256, 0, stream>>>(ws16, out, recip);
  } else {
    const long long nf4 = OUT_TOT / 4;
    dil_scale_f32<<<(int)(nf4 / 256), 256, 0, stream>>>(out, recip);
  }
}